// Round 4
// baseline (222.444 us; speedup 1.0000x reference)
//
#include <hip/hip_runtime.h>

#define S      4096
#define D      512
#define KWIN   3
#define SP     (S + 2)          // zero-padded rows: g = s + tap, g in [0, S+1]
#define MAXOUT 16384
#define EPSLN  1e-5f
#define NIT    16               // i-tiles per tap (512/32)
#define NKT    48               // total K tiles (1536/32)
#define NPAIR  24               // BK=64 pairs

typedef __attribute__((ext_vector_type(8))) short short8;
typedef __attribute__((ext_vector_type(4))) float floatx4;

__device__ inline ushort f2bf(float x) {
  union { float f; unsigned u; } v; v.f = x;
  unsigned r = v.u + 0x7fffu + ((v.u >> 16) & 1u);
  return (ushort)(r >> 16);
}
__device__ inline float bf2f(ushort h) {
  union { float f; unsigned u; } v; v.u = ((unsigned)h) << 16;
  return v.f;
}

// ---------------------------------------------------------------------------
// Packing, fully vectorized: 8 elems/thread, short8 (16B) stores.
//  region 0: enc [S][D] -> Xp hi/lo [NIT][SP][32] with zero pad rows
//  region 1: w1 -> Bp1 hi/lo    region 2: w2 -> Bp2 hi/lo
//  region 3: zero T1 pad rows + zero the ln2 ticket counter
// ---------------------------------------------------------------------------
#define PBX 1025                 // ceil(SP*64 / 256) ; SP*64 = 262272
#define PBW 384                  // 48*512*32/8/256 per weight

__global__ __launch_bounds__(256) void pack_all_kernel(
    const float* __restrict__ x, const float* __restrict__ w1,
    const float* __restrict__ w2, ushort* __restrict__ Xph,
    ushort* __restrict__ Xpl, ushort* __restrict__ B1h, ushort* __restrict__ B1l,
    ushort* __restrict__ B2h, ushort* __restrict__ B2l,
    ushort* __restrict__ T1h, ushort* __restrict__ T1l,
    int* __restrict__ cnt) {
  const int b = blockIdx.x;
  if (b < PBX) {
    const int v = b * 256 + threadIdx.x;        // over SP * (D/8)
    if (v >= SP * 64) return;
    const int g   = v >> 6;
    const int oct = v & 63;
    const int i0  = oct * 8;
    float vv[8];
    if (g == 0 || g == SP - 1) {
#pragma unroll
      for (int j = 0; j < 8; ++j) vv[j] = 0.f;
    } else {
      const float4 a = *(const float4*)(x + (size_t)(g - 1) * D + i0);
      const float4 c = *(const float4*)(x + (size_t)(g - 1) * D + i0 + 4);
      vv[0] = a.x; vv[1] = a.y; vv[2] = a.z; vv[3] = a.w;
      vv[4] = c.x; vv[5] = c.y; vv[6] = c.z; vv[7] = c.w;
    }
    short8 h8, l8;
#pragma unroll
    for (int j = 0; j < 8; ++j) {
      const ushort hi = f2bf(vv[j]);
      h8[j] = (short)hi;
      l8[j] = (short)f2bf(vv[j] - bf2f(hi));
    }
    const size_t dst = ((size_t)(oct >> 2) * SP + g) * 32 + (size_t)(oct & 3) * 8;
    *(short8*)(Xph + dst) = h8;
    *(short8*)(Xpl + dst) = l8;
  } else if (b < PBX + 2 * PBW) {
    const int wsel = (b - PBX) >= PBW;
    const int u = ((b - PBX) - (wsel ? PBW : 0)) * 256 + threadIdx.x;  // < 98304
    const float* __restrict__ w = wsel ? w2 : w1;
    ushort* __restrict__ bh = wsel ? B2h : B1h;
    ushort* __restrict__ bl = wsel ? B2l : B1l;
    const int kk0 = (u & 3) * 8;
    const int o   = (u >> 2) & 511;
    const int it  = (u >> 11) & 15;
    const int k   = u >> 15;                    // 0..2
    const float* __restrict__ src =
        w + (size_t)o * (D * KWIN) + (size_t)(it * 32 + kk0) * KWIN + k;
    short8 h8, l8;
#pragma unroll
    for (int j = 0; j < 8; ++j) {
      const float vv = src[j * KWIN];
      const ushort hi = f2bf(vv);
      h8[j] = (short)hi;
      l8[j] = (short)f2bf(vv - bf2f(hi));
    }
    const size_t idx = (size_t)kk0 + ((size_t)o << 5) + ((size_t)it << 14) +
                       ((size_t)k << 18);
    *(short8*)(bh + idx) = h8;
    *(short8*)(bl + idx) = l8;
  } else {
    const int z = threadIdx.x;                  // T1 pad rows: 16 tiles x 2 rows x 32
    if (z < 128) {
      const int c    = z >> 3;
      const int rr   = (z >> 2) & 1;
      const int colo = (z & 3) * 8;
      const size_t off = ((size_t)c * SP + (rr ? (SP - 1) : 0)) * 32 + colo;
      short8 zero = {};
      *(short8*)(T1h + off) = zero;
      *(short8*)(T1l + off) = zero;
    } else if (z == 128) {
      cnt[0] = 0;                               // ln2 last-block ticket
    }
  }
}

// ---------------------------------------------------------------------------
// MFMA GEMM, fp32-accurate via bf16 hi/lo (hh+hl+lh), double-buffered LDS.
// 128x64 tile (grid 32x8 = 256 blocks = 1 block/CU), BK=64, 8 waves
// (2 waves/SIMD). K-HALF SPLIT: wave = (ms, kh) with ms = wave>>1 owning
// rows [ms*32, ms*32+32) x ALL 64 cols, kh = wave&1 computing only k-subtile
// kh of each BK=64 pair. Per iter per wave: 12 ds_read_b128 -> 24 MFMA
// (0.5 reads/MFMA vs 0.67 before; LDS-BW-bound so this is the lever:
// 128->96 KB LDS read per block-iter, floor ~15 -> ~11.3 us). End: kh=1
// waves dump acc to a 32 KB smem region, kh=0 waves add + store C.
// Staging/barrier schedule unchanged from the verified round-2 kernel.
// ---------------------------------------------------------------------------
#define TM 128
#define TN 64
#define AH_OFF 0                 // [sub][128*32] ushorts
#define AL_OFF 8192
#define BH_OFF 16384             // [sub][64*32]
#define BL_OFF 20480
#define DBUFSZ 24576             // ushorts per double-buffer slot (48 KB)

__device__ inline void gload16(const void* g, void* l) {
  __builtin_amdgcn_global_load_lds((const __attribute__((address_space(1))) void*)g,
                                   (__attribute__((address_space(3))) void*)l,
                                   16, 0, 0);
}

__global__ __launch_bounds__(512) void gemm_mfma_kernel(
    const ushort* __restrict__ Ah, const ushort* __restrict__ Al,
    const ushort* __restrict__ Bh, const ushort* __restrict__ Bl,
    float* __restrict__ C) {
  __shared__ __align__(16) ushort smem[2 * DBUFSZ];   // 96 KB

  const int tid  = threadIdx.x;
  const int wave = tid >> 6;
  const int lane = tid & 63;
  const int ms   = wave >> 1;        // m-slice 0..3
  const int kh   = wave & 1;         // k-half this wave computes
  const int row0 = blockIdx.x * TM;
  const int col0 = blockIdx.y * TN;
  const int wm0  = ms * 32;
  const int fr   = lane & 15;
  const int quad = lane >> 4;

  floatx4 acc[2][4] = {};

  auto stage = [&](int p, int db) {
    ushort* base = smem + db * DBUFSZ;
    if (wave < 4) {
      // waves 0,1 -> Ah sub0,sub1 ; waves 2,3 -> Al sub0,sub1
      const int sub = wave & 1;
      const int kt  = 2 * p + sub;
      const int tap   = kt >> 4;
      const int itile = kt & 15;
      const ushort* gb = (wave < 2 ? Ah : Al) +
                         ((size_t)itile * SP + row0 + tap) * 32;
      ushort* lb = base + (wave < 2 ? AH_OFF : AL_OFF) + sub * 4096;
#pragma unroll
      for (int seg = 0; seg < 8; ++seg)
        gload16(gb + seg * 512 + lane * 8, lb + seg * 512);
    } else if (wave < 6) {
      // wave 4 -> Bh (both subs), wave 5 -> Bl (both subs)
      const ushort* src = (wave == 4 ? Bh : Bl);
      ushort* lb0 = base + (wave == 4 ? BH_OFF : BL_OFF);
#pragma unroll
      for (int sub = 0; sub < 2; ++sub) {
        const int kt = 2 * p + sub;
        const ushort* gb = src + ((size_t)kt * D + col0) * 32;
#pragma unroll
        for (int seg = 0; seg < 4; ++seg)
          gload16(gb + seg * 512 + lane * 8, lb0 + sub * 2048 + seg * 512);
      }
    }
    // waves 6,7: no staging
  };

  stage(0, 0);

  const int soa = kh * 4096;         // this wave's k-subtile offset in A region
  const int sob = kh * 2048;         // and in B region

  for (int p = 0; p < NPAIR; ++p) {
    const int db = p & 1;
    __syncthreads();                 // drains this buffer's loads (vmcnt(0))
    if (p + 1 < NPAIR) stage(p + 1, db ^ 1);

    const int dbo = db * DBUFSZ;
    short8 ah[2], al2[2], bh[4], bl2[4];
#pragma unroll
    for (int mf = 0; mf < 2; ++mf) {
      const int off = soa + (wm0 + mf * 16 + fr) * 32 + quad * 8;
      ah[mf]  = *(const short8*)&smem[dbo + AH_OFF + off];
      al2[mf] = *(const short8*)&smem[dbo + AL_OFF + off];
    }
#pragma unroll
    for (int nf = 0; nf < 4; ++nf) {
      const int offb = sob + (nf * 16 + fr) * 32 + quad * 8;
      bh[nf]  = *(const short8*)&smem[dbo + BH_OFF + offb];
      bl2[nf] = *(const short8*)&smem[dbo + BL_OFF + offb];
    }
#pragma unroll
    for (int mf = 0; mf < 2; ++mf)
#pragma unroll
      for (int nf = 0; nf < 4; ++nf) {
        acc[mf][nf] = __builtin_amdgcn_mfma_f32_16x16x32_bf16(ah[mf],  bh[nf],  acc[mf][nf], 0, 0, 0);
        acc[mf][nf] = __builtin_amdgcn_mfma_f32_16x16x32_bf16(ah[mf],  bl2[nf], acc[mf][nf], 0, 0, 0);
        acc[mf][nf] = __builtin_amdgcn_mfma_f32_16x16x32_bf16(al2[mf], bh[nf],  acc[mf][nf], 0, 0, 0);
      }
  }

  // k-half reduction: kh=1 waves dump to smem (32 KB), kh=0 add + store C.
  __syncthreads();
  float* red = (float*)smem;
  if (kh == 1) {
#pragma unroll
    for (int mf = 0; mf < 2; ++mf)
#pragma unroll
      for (int nf = 0; nf < 4; ++nf)
        *(floatx4*)&red[((((ms * 2 + mf) * 4 + nf) * 64) + lane) * 4] = acc[mf][nf];
  }
  __syncthreads();
  if (kh == 0) {
#pragma unroll
    for (int mf = 0; mf < 2; ++mf)
#pragma unroll
      for (int nf = 0; nf < 4; ++nf) {
        const floatx4 o =
            *(const floatx4*)&red[((((ms * 2 + mf) * 4 + nf) * 64) + lane) * 4];
        acc[mf][nf] += o;
        const int col = col0 + nf * 16 + fr;
#pragma unroll
        for (int r = 0; r < 4; ++r) {
          const int row = row0 + wm0 + mf * 16 + quad * 4 + r;
          C[(size_t)row * D + col] = acc[mf][nf][r];
        }
      }
  }
}

// ---------------------------------------------------------------------------
// (conv_out + conv_bias) -> LayerNorm -> ReLU -> bf16 hi/lo packed (row g=s+1).
// ---------------------------------------------------------------------------
__global__ __launch_bounds__(256) void ln_relu_pack_kernel(
    const float* __restrict__ X, const float* __restrict__ cb,
    const float* __restrict__ gam, const float* __restrict__ bet,
    ushort* __restrict__ th, ushort* __restrict__ tl) {
  const int wave = threadIdx.x >> 6;
  const int lane = threadIdx.x & 63;
  const int s = blockIdx.x * 4 + wave;
  const float4* xp = (const float4*)(X + (size_t)s * D);
  float4 a = xp[2 * lane];
  float4 b = xp[2 * lane + 1];
  const float4 ca  = ((const float4*)cb)[2 * lane];
  const float4 cb2 = ((const float4*)cb)[2 * lane + 1];
  float v[8] = {a.x + ca.x,  a.y + ca.y,  a.z + ca.z,  a.w + ca.w,
                b.x + cb2.x, b.y + cb2.y, b.z + cb2.z, b.w + cb2.w};
  float sum = 0.f;
#pragma unroll
  for (int i = 0; i < 8; ++i) sum += v[i];
#pragma unroll
  for (int off = 32; off > 0; off >>= 1) sum += __shfl_xor(sum, off);
  const float m = sum * (1.0f / D);
  float sq = 0.f;
#pragma unroll
  for (int i = 0; i < 8; ++i) { v[i] -= m; sq += v[i] * v[i]; }
#pragma unroll
  for (int off = 32; off > 0; off >>= 1) sq += __shfl_xor(sq, off);
  const float rs = rsqrtf(sq * (1.0f / D) + EPSLN);
  const float4 ga = ((const float4*)gam)[2 * lane];
  const float4 gb = ((const float4*)gam)[2 * lane + 1];
  const float4 ba = ((const float4*)bet)[2 * lane];
  const float4 bb = ((const float4*)bet)[2 * lane + 1];
  const float gg[8] = {ga.x, ga.y, ga.z, ga.w, gb.x, gb.y, gb.z, gb.w};
  const float bt[8] = {ba.x, ba.y, ba.z, ba.w, bb.x, bb.y, bb.z, bb.w};
  short8 h8, l8;
#pragma unroll
  for (int i = 0; i < 8; ++i) {
    float y = fmaxf(v[i] * rs * gg[i] + bt[i], 0.0f);
    ushort hi = f2bf(y);
    h8[i] = (short)hi;
    l8[i] = (short)f2bf(y - bf2f(hi));
  }
  const size_t base = ((size_t)(lane >> 2) * SP + (s + 1)) * 32 + (size_t)(lane & 3) * 8;
  *(short8*)(th + base) = h8;
  *(short8*)(tl + base) = l8;
}

// ---------------------------------------------------------------------------
// (conv2_out + bias) -> LN -> ReLU -> dot(lw) -> relu -> dur = floor(p + 0.5)
// FUSED SCAN: last-block-done ticket (threadfence + device atomic); the
// 1024th block to finish runs the 1-wave inclusive scan of dur -> cum.
// rocPRIM-style decoupled pattern; cnt zeroed by pack_all (stream-ordered).
// ---------------------------------------------------------------------------
__global__ __launch_bounds__(256) void ln2_pred_scan_kernel(
    const float* __restrict__ X, const float* __restrict__ cb,
    const float* __restrict__ gam, const float* __restrict__ bet,
    const float* __restrict__ lw, const float* __restrict__ lb,
    int* __restrict__ dur, int* __restrict__ cum, int* __restrict__ cnt) {
  const int wave = threadIdx.x >> 6;
  const int lane = threadIdx.x & 63;
  const int s = blockIdx.x * 4 + wave;
  const float4* xp = (const float4*)(X + (size_t)s * D);
  float4 a = xp[2 * lane];
  float4 b = xp[2 * lane + 1];
  const float4 ca  = ((const float4*)cb)[2 * lane];
  const float4 cb2 = ((const float4*)cb)[2 * lane + 1];
  float v[8] = {a.x + ca.x,  a.y + ca.y,  a.z + ca.z,  a.w + ca.w,
                b.x + cb2.x, b.y + cb2.y, b.z + cb2.z, b.w + cb2.w};
  float sum = 0.f;
#pragma unroll
  for (int i = 0; i < 8; ++i) sum += v[i];
#pragma unroll
  for (int off = 32; off > 0; off >>= 1) sum += __shfl_xor(sum, off);
  const float m = sum * (1.0f / D);
  float sq = 0.f;
#pragma unroll
  for (int i = 0; i < 8; ++i) { v[i] -= m; sq += v[i] * v[i]; }
#pragma unroll
  for (int off = 32; off > 0; off >>= 1) sq += __shfl_xor(sq, off);
  const float rs = rsqrtf(sq * (1.0f / D) + EPSLN);
  const float4 ga = ((const float4*)gam)[2 * lane];
  const float4 gb = ((const float4*)gam)[2 * lane + 1];
  const float4 ba = ((const float4*)bet)[2 * lane];
  const float4 bb = ((const float4*)bet)[2 * lane + 1];
  const float gg[8] = {ga.x, ga.y, ga.z, ga.w, gb.x, gb.y, gb.z, gb.w};
  const float bt[8] = {ba.x, ba.y, ba.z, ba.w, bb.x, bb.y, bb.z, bb.w};
  const float4 w0 = ((const float4*)lw)[2 * lane];
  const float4 w1 = ((const float4*)lw)[2 * lane + 1];
  const float ww[8] = {w0.x, w0.y, w0.z, w0.w, w1.x, w1.y, w1.z, w1.w};
  float d = 0.f;
#pragma unroll
  for (int i = 0; i < 8; ++i) {
    float y = fmaxf(v[i] * rs * gg[i] + bt[i], 0.0f);
    d += y * ww[i];
  }
#pragma unroll
  for (int off = 32; off > 0; off >>= 1) d += __shfl_xor(d, off);
  if (lane == 0) {
    const float p = fmaxf(d + lb[0], 0.0f);
    dur[s] = (int)floorf(p + 0.5f);
  }

  // ---- last-block ticket, then 1-wave scan of dur -> cum ----
  __syncthreads();
  __threadfence();                       // release dur stores (device scope)
  __shared__ int ticket;
  if (threadIdx.x == 0) ticket = atomicAdd(cnt, 1);
  __syncthreads();
  if (ticket != (S / 4) - 1) return;
  __threadfence();                       // acquire before reading all dur
  if (threadIdx.x >= 64) return;
  const int l = threadIdx.x;
  const int4* src = (const int4*)dur + (size_t)l * 16;
  int4 vv[16];
  int run = 0;
#pragma unroll
  for (int i = 0; i < 16; ++i) {
    int4 dd = src[i];
    dd.x += run; dd.y += dd.x; dd.z += dd.y; dd.w += dd.z;
    run = dd.w;
    vv[i] = dd;
  }
  int sc = run;
#pragma unroll
  for (int off = 1; off < 64; off <<= 1) {
    const int n = __shfl_up(sc, off);
    if (l >= off) sc += n;
  }
  const int base = sc - run;   // exclusive prefix of this lane's chunk
  int4* dst = (int4*)cum + (size_t)l * 16;
#pragma unroll
  for (int i = 0; i < 16; ++i) {
    int4 dd = vv[i];
    dd.x += base; dd.y += base; dd.z += base; dd.w += base;
    dst[i] = dd;
  }
}

// ---------------------------------------------------------------------------
// Length-regulate gather. 2 frames per 256-thread block.
// ---------------------------------------------------------------------------
__global__ __launch_bounds__(256) void gather_kernel(
    const float* __restrict__ enc, const int* __restrict__ cum,
    float* __restrict__ out0, float* __restrict__ out1) {
  const int half = threadIdx.x >> 7;
  const int d4   = (threadIdx.x & 127) << 2;
  const int t    = blockIdx.x * 2 + half;
  const int total = cum[S - 1];

  int lo = 0, hi = S;
  while (lo < hi) {
    const int mid = (lo + hi) >> 1;
    if (cum[mid] <= t) lo = mid + 1; else hi = mid;
  }
  const int idx = (lo < S) ? lo : (S - 1);

  float4 v = make_float4(0.f, 0.f, 0.f, 0.f);
  if (t < total) v = *(const float4*)(enc + (size_t)idx * D + d4);
  *(float4*)(out0 + (size_t)t * D + d4) = v;

  if ((threadIdx.x & 127) == 0) out1[t] = (float)(t + 1);
}

// ---------------------------------------------------------------------------
extern "C" void kernel_launch(void* const* d_in, const int* in_sizes, int n_in,
                              void* d_out, int out_size, void* d_ws, size_t ws_size,
                              hipStream_t stream) {
  const float* enc = (const float*)d_in[0];
  const float* w1  = (const float*)d_in[1];
  const float* cb1 = (const float*)d_in[2];
  const float* g1  = (const float*)d_in[3];
  const float* be1 = (const float*)d_in[4];
  const float* w2  = (const float*)d_in[5];
  const float* cb2 = (const float*)d_in[6];
  const float* g2  = (const float*)d_in[7];
  const float* be2 = (const float*)d_in[8];
  const float* lw  = (const float*)d_in[9];
  const float* lb  = (const float*)d_in[10];

  float* out0 = (float*)d_out;                 // [MAXOUT, D]
  float* out1 = out0 + (size_t)MAXOUT * D;     // [MAXOUT]

  const size_t NP = (size_t)NIT * SP * 32;     // packed activation elems
  const size_t NB = (size_t)NKT * D * 32;      // packed weight elems
  ushort* Xph = (ushort*)d_ws;
  ushort* Xpl = Xph + NP;
  ushort* T1h = Xpl + NP;
  ushort* T1l = T1h + NP;
  ushort* B1h = T1l + NP;
  ushort* B1l = B1h + NB;
  ushort* B2h = B1l + NB;
  ushort* B2l = B2h + NB;
  float*  t0  = (float*)(B2l + NB);            // S*D fp32
  int*   dur  = (int*)(t0 + (size_t)S * D);
  int*   cum  = dur + S;
  int*   cnt  = cum + S;

  pack_all_kernel<<<PBX + 2 * PBW + 1, 256, 0, stream>>>(
      enc, w1, w2, Xph, Xpl, B1h, B1l, B2h, B2l, T1h, T1l, cnt);
  gemm_mfma_kernel<<<dim3(S / TM, D / TN), 512, 0, stream>>>(Xph, Xpl, B1h, B1l, t0);
  ln_relu_pack_kernel<<<S / 4, 256, 0, stream>>>(t0, cb1, g1, be1, T1h, T1l);
  gemm_mfma_kernel<<<dim3(S / TM, D / TN), 512, 0, stream>>>(T1h, T1l, B2h, B2l, t0);
  ln2_pred_scan_kernel<<<S / 4, 256, 0, stream>>>(t0, cb2, g2, be2, lw, lb, dur, cum, cnt);
  gather_kernel<<<MAXOUT / 2, 256, 0, stream>>>(enc, cum, out0, out1);
}

// Round 5
// 162.549 us; speedup vs baseline: 1.3685x; 1.3685x over previous
//
#include <hip/hip_runtime.h>

#define S      4096
#define D      512
#define KWIN   3
#define SP     (S + 2)          // zero-padded rows: g = s + tap, g in [0, S+1]
#define MAXOUT 16384
#define EPSLN  1e-5f
#define NIT    16               // i-tiles per tap (512/32)
#define NKT    48               // total K tiles (1536/32)
#define NPAIR  24               // BK=64 pairs

typedef __attribute__((ext_vector_type(8))) short short8;
typedef __attribute__((ext_vector_type(4))) float floatx4;

__device__ inline ushort f2bf(float x) {
  union { float f; unsigned u; } v; v.f = x;
  unsigned r = v.u + 0x7fffu + ((v.u >> 16) & 1u);
  return (ushort)(r >> 16);
}
__device__ inline float bf2f(ushort h) {
  union { float f; unsigned u; } v; v.u = ((unsigned)h) << 16;
  return v.f;
}

// ---------------------------------------------------------------------------
// Packing, fully vectorized: 8 elems/thread, short8 (16B) stores.
//  region 0: enc [S][D] -> Xp hi/lo [NIT][SP][32] with zero pad rows
//  region 1: w1 -> Bp1 hi/lo    region 2: w2 -> Bp2 hi/lo
//  region 3: zero T1 pad rows
// ---------------------------------------------------------------------------
#define PBX 1025                 // ceil(SP*64 / 256) ; SP*64 = 262272
#define PBW 384                  // 48*512*32/8/256 per weight

__global__ __launch_bounds__(256) void pack_all_kernel(
    const float* __restrict__ x, const float* __restrict__ w1,
    const float* __restrict__ w2, ushort* __restrict__ Xph,
    ushort* __restrict__ Xpl, ushort* __restrict__ B1h, ushort* __restrict__ B1l,
    ushort* __restrict__ B2h, ushort* __restrict__ B2l,
    ushort* __restrict__ T1h, ushort* __restrict__ T1l) {
  const int b = blockIdx.x;
  if (b < PBX) {
    const int v = b * 256 + threadIdx.x;        // over SP * (D/8)
    if (v >= SP * 64) return;
    const int g   = v >> 6;
    const int oct = v & 63;
    const int i0  = oct * 8;
    float vv[8];
    if (g == 0 || g == SP - 1) {
#pragma unroll
      for (int j = 0; j < 8; ++j) vv[j] = 0.f;
    } else {
      const float4 a = *(const float4*)(x + (size_t)(g - 1) * D + i0);
      const float4 c = *(const float4*)(x + (size_t)(g - 1) * D + i0 + 4);
      vv[0] = a.x; vv[1] = a.y; vv[2] = a.z; vv[3] = a.w;
      vv[4] = c.x; vv[5] = c.y; vv[6] = c.z; vv[7] = c.w;
    }
    short8 h8, l8;
#pragma unroll
    for (int j = 0; j < 8; ++j) {
      const ushort hi = f2bf(vv[j]);
      h8[j] = (short)hi;
      l8[j] = (short)f2bf(vv[j] - bf2f(hi));
    }
    const size_t dst = ((size_t)(oct >> 2) * SP + g) * 32 + (size_t)(oct & 3) * 8;
    *(short8*)(Xph + dst) = h8;
    *(short8*)(Xpl + dst) = l8;
  } else if (b < PBX + 2 * PBW) {
    const int wsel = (b - PBX) >= PBW;
    const int u = ((b - PBX) - (wsel ? PBW : 0)) * 256 + threadIdx.x;  // < 98304
    const float* __restrict__ w = wsel ? w2 : w1;
    ushort* __restrict__ bh = wsel ? B2h : B1h;
    ushort* __restrict__ bl = wsel ? B2l : B1l;
    const int kk0 = (u & 3) * 8;
    const int o   = (u >> 2) & 511;
    const int it  = (u >> 11) & 15;
    const int k   = u >> 15;                    // 0..2
    const float* __restrict__ src =
        w + (size_t)o * (D * KWIN) + (size_t)(it * 32 + kk0) * KWIN + k;
    short8 h8, l8;
#pragma unroll
    for (int j = 0; j < 8; ++j) {
      const float vv = src[j * KWIN];
      const ushort hi = f2bf(vv);
      h8[j] = (short)hi;
      l8[j] = (short)f2bf(vv - bf2f(hi));
    }
    const size_t idx = (size_t)kk0 + ((size_t)o << 5) + ((size_t)it << 14) +
                       ((size_t)k << 18);
    *(short8*)(bh + idx) = h8;
    *(short8*)(bl + idx) = l8;
  } else {
    const int z = threadIdx.x;                  // T1 pad rows: 16 tiles x 2 rows x 32
    if (z < 128) {
      const int c    = z >> 3;
      const int rr   = (z >> 2) & 1;
      const int colo = (z & 3) * 8;
      const size_t off = ((size_t)c * SP + (rr ? (SP - 1) : 0)) * 32 + colo;
      short8 zero = {};
      *(short8*)(T1h + off) = zero;
      *(short8*)(T1l + off) = zero;
    }
  }
}

// ---------------------------------------------------------------------------
// MFMA GEMM, fp32-accurate via bf16 hi/lo (hh+hl+lh), double-buffered LDS.
// 128x64 tile (grid 32x8 = 256 blocks = 1 block/CU), BK=64, 8 waves
// (2 waves/SIMD). K-HALF SPLIT: wave = (ms, kh) with ms = wave>>1 owning
// rows [ms*32, ms*32+32) x ALL 64 cols, kh = wave&1 computing only k-subtile
// kh of each BK=64 pair. Per iter per wave: 12 ds_read_b128 -> 24 MFMA
// (0.5 reads/MFMA; LDS-BW-bound so this is the lever: 128->96 KB LDS read
// per block-iter). End: kh=1 waves dump acc to smem, kh=0 add + store C.
// NOTE round-4 lesson: per-block device-scope __threadfence() costs ~65 ns
// SERIALIZED device-wide — never fuse cross-block sync into wide kernels.
// ---------------------------------------------------------------------------
#define TM 128
#define TN 64
#define AH_OFF 0                 // [sub][128*32] ushorts
#define AL_OFF 8192
#define BH_OFF 16384             // [sub][64*32]
#define BL_OFF 20480
#define DBUFSZ 24576             // ushorts per double-buffer slot (48 KB)

__device__ inline void gload16(const void* g, void* l) {
  __builtin_amdgcn_global_load_lds((const __attribute__((address_space(1))) void*)g,
                                   (__attribute__((address_space(3))) void*)l,
                                   16, 0, 0);
}

__global__ __launch_bounds__(512) void gemm_mfma_kernel(
    const ushort* __restrict__ Ah, const ushort* __restrict__ Al,
    const ushort* __restrict__ Bh, const ushort* __restrict__ Bl,
    float* __restrict__ C) {
  __shared__ __align__(16) ushort smem[2 * DBUFSZ];   // 96 KB

  const int tid  = threadIdx.x;
  const int wave = tid >> 6;
  const int lane = tid & 63;
  const int ms   = wave >> 1;        // m-slice 0..3
  const int kh   = wave & 1;         // k-half this wave computes
  const int row0 = blockIdx.x * TM;
  const int col0 = blockIdx.y * TN;
  const int wm0  = ms * 32;
  const int fr   = lane & 15;
  const int quad = lane >> 4;

  floatx4 acc[2][4] = {};

  auto stage = [&](int p, int db) {
    ushort* base = smem + db * DBUFSZ;
    if (wave < 4) {
      // waves 0,1 -> Ah sub0,sub1 ; waves 2,3 -> Al sub0,sub1
      const int sub = wave & 1;
      const int kt  = 2 * p + sub;
      const int tap   = kt >> 4;
      const int itile = kt & 15;
      const ushort* gb = (wave < 2 ? Ah : Al) +
                         ((size_t)itile * SP + row0 + tap) * 32;
      ushort* lb = base + (wave < 2 ? AH_OFF : AL_OFF) + sub * 4096;
#pragma unroll
      for (int seg = 0; seg < 8; ++seg)
        gload16(gb + seg * 512 + lane * 8, lb + seg * 512);
    } else if (wave < 6) {
      // wave 4 -> Bh (both subs), wave 5 -> Bl (both subs)
      const ushort* src = (wave == 4 ? Bh : Bl);
      ushort* lb0 = base + (wave == 4 ? BH_OFF : BL_OFF);
#pragma unroll
      for (int sub = 0; sub < 2; ++sub) {
        const int kt = 2 * p + sub;
        const ushort* gb = src + ((size_t)kt * D + col0) * 32;
#pragma unroll
        for (int seg = 0; seg < 4; ++seg)
          gload16(gb + seg * 512 + lane * 8, lb0 + sub * 2048 + seg * 512);
      }
    }
    // waves 6,7: no staging
  };

  stage(0, 0);

  const int soa = kh * 4096;         // this wave's k-subtile offset in A region
  const int sob = kh * 2048;         // and in B region

  for (int p = 0; p < NPAIR; ++p) {
    const int db = p & 1;
    __syncthreads();                 // drains this buffer's loads (vmcnt(0))
    if (p + 1 < NPAIR) stage(p + 1, db ^ 1);

    const int dbo = db * DBUFSZ;
    short8 ah[2], al2[2], bh[4], bl2[4];
#pragma unroll
    for (int mf = 0; mf < 2; ++mf) {
      const int off = soa + (wm0 + mf * 16 + fr) * 32 + quad * 8;
      ah[mf]  = *(const short8*)&smem[dbo + AH_OFF + off];
      al2[mf] = *(const short8*)&smem[dbo + AL_OFF + off];
    }
#pragma unroll
    for (int nf = 0; nf < 4; ++nf) {
      const int offb = sob + (nf * 16 + fr) * 32 + quad * 8;
      bh[nf]  = *(const short8*)&smem[dbo + BH_OFF + offb];
      bl2[nf] = *(const short8*)&smem[dbo + BL_OFF + offb];
    }
#pragma unroll
    for (int mf = 0; mf < 2; ++mf)
#pragma unroll
      for (int nf = 0; nf < 4; ++nf) {
        acc[mf][nf] = __builtin_amdgcn_mfma_f32_16x16x32_bf16(ah[mf],  bh[nf],  acc[mf][nf], 0, 0, 0);
        acc[mf][nf] = __builtin_amdgcn_mfma_f32_16x16x32_bf16(ah[mf],  bl2[nf], acc[mf][nf], 0, 0, 0);
        acc[mf][nf] = __builtin_amdgcn_mfma_f32_16x16x32_bf16(al2[mf], bh[nf],  acc[mf][nf], 0, 0, 0);
      }
  }

  // k-half reduction: kh=1 waves dump to smem (32 KB), kh=0 add + store C.
  __syncthreads();
  float* red = (float*)smem;
  if (kh == 1) {
#pragma unroll
    for (int mf = 0; mf < 2; ++mf)
#pragma unroll
      for (int nf = 0; nf < 4; ++nf)
        *(floatx4*)&red[((((ms * 2 + mf) * 4 + nf) * 64) + lane) * 4] = acc[mf][nf];
  }
  __syncthreads();
  if (kh == 0) {
#pragma unroll
    for (int mf = 0; mf < 2; ++mf)
#pragma unroll
      for (int nf = 0; nf < 4; ++nf) {
        const floatx4 o =
            *(const floatx4*)&red[((((ms * 2 + mf) * 4 + nf) * 64) + lane) * 4];
        acc[mf][nf] += o;
        const int col = col0 + nf * 16 + fr;
#pragma unroll
        for (int r = 0; r < 4; ++r) {
          const int row = row0 + wm0 + mf * 16 + quad * 4 + r;
          C[(size_t)row * D + col] = acc[mf][nf][r];
        }
      }
  }
}

// ---------------------------------------------------------------------------
// (conv_out + conv_bias) -> LayerNorm -> ReLU -> bf16 hi/lo packed (row g=s+1).
// ---------------------------------------------------------------------------
__global__ __launch_bounds__(256) void ln_relu_pack_kernel(
    const float* __restrict__ X, const float* __restrict__ cb,
    const float* __restrict__ gam, const float* __restrict__ bet,
    ushort* __restrict__ th, ushort* __restrict__ tl) {
  const int wave = threadIdx.x >> 6;
  const int lane = threadIdx.x & 63;
  const int s = blockIdx.x * 4 + wave;
  const float4* xp = (const float4*)(X + (size_t)s * D);
  float4 a = xp[2 * lane];
  float4 b = xp[2 * lane + 1];
  const float4 ca  = ((const float4*)cb)[2 * lane];
  const float4 cb2 = ((const float4*)cb)[2 * lane + 1];
  float v[8] = {a.x + ca.x,  a.y + ca.y,  a.z + ca.z,  a.w + ca.w,
                b.x + cb2.x, b.y + cb2.y, b.z + cb2.z, b.w + cb2.w};
  float sum = 0.f;
#pragma unroll
  for (int i = 0; i < 8; ++i) sum += v[i];
#pragma unroll
  for (int off = 32; off > 0; off >>= 1) sum += __shfl_xor(sum, off);
  const float m = sum * (1.0f / D);
  float sq = 0.f;
#pragma unroll
  for (int i = 0; i < 8; ++i) { v[i] -= m; sq += v[i] * v[i]; }
#pragma unroll
  for (int off = 32; off > 0; off >>= 1) sq += __shfl_xor(sq, off);
  const float rs = rsqrtf(sq * (1.0f / D) + EPSLN);
  const float4 ga = ((const float4*)gam)[2 * lane];
  const float4 gb = ((const float4*)gam)[2 * lane + 1];
  const float4 ba = ((const float4*)bet)[2 * lane];
  const float4 bb = ((const float4*)bet)[2 * lane + 1];
  const float gg[8] = {ga.x, ga.y, ga.z, ga.w, gb.x, gb.y, gb.z, gb.w};
  const float bt[8] = {ba.x, ba.y, ba.z, ba.w, bb.x, bb.y, bb.z, bb.w};
  short8 h8, l8;
#pragma unroll
  for (int i = 0; i < 8; ++i) {
    float y = fmaxf(v[i] * rs * gg[i] + bt[i], 0.0f);
    ushort hi = f2bf(y);
    h8[i] = (short)hi;
    l8[i] = (short)f2bf(y - bf2f(hi));
  }
  const size_t base = ((size_t)(lane >> 2) * SP + (s + 1)) * 32 + (size_t)(lane & 3) * 8;
  *(short8*)(th + base) = h8;
  *(short8*)(tl + base) = l8;
}

// ---------------------------------------------------------------------------
// (conv2_out + bias) -> LN -> ReLU -> dot(lw) -> relu -> dur = floor(p + 0.5)
// ---------------------------------------------------------------------------
__global__ __launch_bounds__(256) void ln2_pred_kernel(
    const float* __restrict__ X, const float* __restrict__ cb,
    const float* __restrict__ gam, const float* __restrict__ bet,
    const float* __restrict__ lw, const float* __restrict__ lb,
    int* __restrict__ dur) {
  const int wave = threadIdx.x >> 6;
  const int lane = threadIdx.x & 63;
  const int s = blockIdx.x * 4 + wave;
  const float4* xp = (const float4*)(X + (size_t)s * D);
  float4 a = xp[2 * lane];
  float4 b = xp[2 * lane + 1];
  const float4 ca  = ((const float4*)cb)[2 * lane];
  const float4 cb2 = ((const float4*)cb)[2 * lane + 1];
  float v[8] = {a.x + ca.x,  a.y + ca.y,  a.z + ca.z,  a.w + ca.w,
                b.x + cb2.x, b.y + cb2.y, b.z + cb2.z, b.w + cb2.w};
  float sum = 0.f;
#pragma unroll
  for (int i = 0; i < 8; ++i) sum += v[i];
#pragma unroll
  for (int off = 32; off > 0; off >>= 1) sum += __shfl_xor(sum, off);
  const float m = sum * (1.0f / D);
  float sq = 0.f;
#pragma unroll
  for (int i = 0; i < 8; ++i) { v[i] -= m; sq += v[i] * v[i]; }
#pragma unroll
  for (int off = 32; off > 0; off >>= 1) sq += __shfl_xor(sq, off);
  const float rs = rsqrtf(sq * (1.0f / D) + EPSLN);
  const float4 ga = ((const float4*)gam)[2 * lane];
  const float4 gb = ((const float4*)gam)[2 * lane + 1];
  const float4 ba = ((const float4*)bet)[2 * lane];
  const float4 bb = ((const float4*)bet)[2 * lane + 1];
  const float gg[8] = {ga.x, ga.y, ga.z, ga.w, gb.x, gb.y, gb.z, gb.w};
  const float bt[8] = {ba.x, ba.y, ba.z, ba.w, bb.x, bb.y, bb.z, bb.w};
  const float4 w0 = ((const float4*)lw)[2 * lane];
  const float4 w1 = ((const float4*)lw)[2 * lane + 1];
  const float ww[8] = {w0.x, w0.y, w0.z, w0.w, w1.x, w1.y, w1.z, w1.w};
  float d = 0.f;
#pragma unroll
  for (int i = 0; i < 8; ++i) {
    float y = fmaxf(v[i] * rs * gg[i] + bt[i], 0.0f);
    d += y * ww[i];
  }
#pragma unroll
  for (int off = 32; off > 0; off >>= 1) d += __shfl_xor(d, off);
  if (lane == 0) {
    const float p = fmaxf(d + lb[0], 0.0f);
    dur[s] = (int)floorf(p + 0.5f);
  }
}

// ---------------------------------------------------------------------------
// Inclusive scan of S=4096 ints with ONE wave: 64 elems/lane serial, then
// 6-step shuffle scan of lane totals. Latency ~2 us.
// ---------------------------------------------------------------------------
__global__ __launch_bounds__(64) void scan_kernel(const int* __restrict__ dur,
                                                  int* __restrict__ cum) {
  const int lane = threadIdx.x;
  const int4* src = (const int4*)dur + (size_t)lane * 16;
  int4 v[16];
  int run = 0;
#pragma unroll
  for (int i = 0; i < 16; ++i) {
    int4 d = src[i];
    d.x += run; d.y += d.x; d.z += d.y; d.w += d.z;
    run = d.w;
    v[i] = d;
  }
  int sc = run;
#pragma unroll
  for (int off = 1; off < 64; off <<= 1) {
    const int n = __shfl_up(sc, off);
    if (lane >= off) sc += n;
  }
  const int base = sc - run;   // exclusive prefix of this lane's chunk
  int4* dst = (int4*)cum + (size_t)lane * 16;
#pragma unroll
  for (int i = 0; i < 16; ++i) {
    int4 d = v[i];
    d.x += base; d.y += base; d.z += base; d.w += base;
    dst[i] = d;
  }
}

// ---------------------------------------------------------------------------
// Length-regulate gather. 2 frames per 256-thread block.
// ---------------------------------------------------------------------------
__global__ __launch_bounds__(256) void gather_kernel(
    const float* __restrict__ enc, const int* __restrict__ cum,
    float* __restrict__ out0, float* __restrict__ out1) {
  const int half = threadIdx.x >> 7;
  const int d4   = (threadIdx.x & 127) << 2;
  const int t    = blockIdx.x * 2 + half;
  const int total = cum[S - 1];

  int lo = 0, hi = S;
  while (lo < hi) {
    const int mid = (lo + hi) >> 1;
    if (cum[mid] <= t) lo = mid + 1; else hi = mid;
  }
  const int idx = (lo < S) ? lo : (S - 1);

  float4 v = make_float4(0.f, 0.f, 0.f, 0.f);
  if (t < total) v = *(const float4*)(enc + (size_t)idx * D + d4);
  *(float4*)(out0 + (size_t)t * D + d4) = v;

  if ((threadIdx.x & 127) == 0) out1[t] = (float)(t + 1);
}

// ---------------------------------------------------------------------------
extern "C" void kernel_launch(void* const* d_in, const int* in_sizes, int n_in,
                              void* d_out, int out_size, void* d_ws, size_t ws_size,
                              hipStream_t stream) {
  const float* enc = (const float*)d_in[0];
  const float* w1  = (const float*)d_in[1];
  const float* cb1 = (const float*)d_in[2];
  const float* g1  = (const float*)d_in[3];
  const float* be1 = (const float*)d_in[4];
  const float* w2  = (const float*)d_in[5];
  const float* cb2 = (const float*)d_in[6];
  const float* g2  = (const float*)d_in[7];
  const float* be2 = (const float*)d_in[8];
  const float* lw  = (const float*)d_in[9];
  const float* lb  = (const float*)d_in[10];

  float* out0 = (float*)d_out;                 // [MAXOUT, D]
  float* out1 = out0 + (size_t)MAXOUT * D;     // [MAXOUT]

  const size_t NP = (size_t)NIT * SP * 32;     // packed activation elems
  const size_t NB = (size_t)NKT * D * 32;      // packed weight elems
  ushort* Xph = (ushort*)d_ws;
  ushort* Xpl = Xph + NP;
  ushort* T1h = Xpl + NP;
  ushort* T1l = T1h + NP;
  ushort* B1h = T1l + NP;
  ushort* B1l = B1h + NB;
  ushort* B2h = B1l + NB;
  ushort* B2l = B2h + NB;
  float*  t0  = (float*)(B2l + NB);            // S*D fp32
  int*   dur  = (int*)(t0 + (size_t)S * D);
  int*   cum  = dur + S;

  pack_all_kernel<<<PBX + 2 * PBW + 1, 256, 0, stream>>>(
      enc, w1, w2, Xph, Xpl, B1h, B1l, B2h, B2l, T1h, T1l);
  gemm_mfma_kernel<<<dim3(S / TM, D / TN), 512, 0, stream>>>(Xph, Xpl, B1h, B1l, t0);
  ln_relu_pack_kernel<<<S / 4, 256, 0, stream>>>(t0, cb1, g1, be1, T1h, T1l);
  gemm_mfma_kernel<<<dim3(S / TM, D / TN), 512, 0, stream>>>(T1h, T1l, B2h, B2l, t0);
  ln2_pred_kernel<<<S / 4, 256, 0, stream>>>(t0, cb2, g2, be2, lw, lb, dur);
  scan_kernel<<<1, 64, 0, stream>>>(dur, cum);
  gather_kernel<<<MAXOUT / 2, 256, 0, stream>>>(enc, cum, out0, out1);
}